// Round 1
// baseline (354.477 us; speedup 1.0000x reference)
//
#include <hip/hip_runtime.h>

// Problem constants
#define NB 512
#define NTOK 128
#define NC 384
#define NH 6
#define ND 64

typedef short s16x8 __attribute__((ext_vector_type(8)));
typedef float f32x4 __attribute__((ext_vector_type(4)));

#define MFMA16(a, b, c) __builtin_amdgcn_mfma_f32_16x16x32_bf16((a), (b), (c), 0, 0, 0)

static __device__ __forceinline__ unsigned short f2bf(float f) {
  unsigned int u = __builtin_bit_cast(unsigned int, f);
  u = (u + 0x7FFFu + ((u >> 16) & 1u)) >> 16;   // RNE truncate to bf16
  return (unsigned short)u;
}

// ---------------- kernel 0: convert + transpose weights to bf16 ----------------
// wqkvT layout: [m][h][d][c]  (m in {q,k,v}) -> B-fragment reads are 8 contiguous c
// wpT   layout: [c_out][j]                   -> B-fragment reads are 8 contiguous j
__global__ __launch_bounds__(256) void convert_weights(
    const float* __restrict__ Wq, const float* __restrict__ Wk,
    const float* __restrict__ Wv, const float* __restrict__ Wp,
    unsigned short* __restrict__ wqkvT, unsigned short* __restrict__ wpT) {
  int idx = blockIdx.x * 256 + threadIdx.x;
  const int NQKV = 3 * NH * ND * NC;  // 442368
  if (idx < NQKV) {
    int c = idx % NC;
    int d = (idx / NC) % ND;
    int h = (idx / (NC * ND)) % NH;
    int m = idx / (NC * ND * NH);
    const float* W = (m == 0) ? Wq : (m == 1) ? Wk : Wv;
    wqkvT[idx] = f2bf(W[(h * NC + c) * ND + d]);
  } else {
    int j = idx - NQKV;               // 0 .. NC*NC-1
    int cc = j / NC, r = j % NC;      // wpT[cc][r] = Wp[r][cc]
    wpT[j] = f2bf(Wp[r * NC + cc]);
  }
}

// ---------------- kernel 1: fused QKV + causal softmax + PV per (b,h) ----------------
struct SP1 { unsigned short xs[128][40]; unsigned short w[3][64][40]; };  // 25600 B
struct SP3 { unsigned short p[128][72]; };                               // 18432 B

__global__ __launch_bounds__(256, 2) void attn_fused(
    const float* __restrict__ x, const unsigned short* __restrict__ wqkvT,
    unsigned short* __restrict__ O) {
  const int h = blockIdx.x >> 9;    // h-major: 6 blocks sharing x[b] are 512 apart -> same XCD
  const int b = blockIdx.x & 511;
  const int tid = threadIdx.x;
  const int lane = tid & 63;
  const int l15 = lane & 15;
  const int lg = lane >> 4;         // 0..3
  const int r0 = (tid >> 6) * 32;   // wave's 32-row stripe

  __shared__ __align__(16) union { SP1 p1; SP3 p3; } su;
  __shared__ __align__(16) unsigned short qs[128][72];   // 18432 B
  __shared__ __align__(16) unsigned short ks[128][72];   // 18432 B
  __shared__ __align__(16) unsigned short vts[64][144];  // 18432 B (V^T, s-contiguous)

  f32x4 accq[2][4], acck[2][4], accv[2][4];
#pragma unroll
  for (int i = 0; i < 2; ++i)
#pragma unroll
    for (int j = 0; j < 4; ++j) {
      accq[i][j] = f32x4{0.f, 0.f, 0.f, 0.f};
      acck[i][j] = f32x4{0.f, 0.f, 0.f, 0.f};
      accv[i][j] = f32x4{0.f, 0.f, 0.f, 0.f};
    }

  const float* xb = x + (size_t)b * (NTOK * NC);
  const unsigned short* wb = wqkvT + h * (ND * NC);

  const int xr = tid >> 3;           // 0..31
  const int xc = (tid & 7) * 4;      // 0,4,..,28
  const int wn = tid >> 2;           // 0..63
  const int wc = (tid & 3) * 8;      // 0,8,16,24

  // ---- phase 1: Q,K,V = x @ W (K-loop over C in chunks of 32) ----
  for (int kc = 0; kc < 12; ++kc) {
    const int c0 = kc * 32;
    __syncthreads();
    // stage x chunk (fp32 -> bf16)
#pragma unroll
    for (int s = 0; s < 4; ++s) {
      int row = xr + 32 * s;
      float4 f = *(const float4*)(xb + row * NC + c0 + xc);
      union { unsigned short h4[4]; uint2 u; } t;
      t.h4[0] = f2bf(f.x); t.h4[1] = f2bf(f.y); t.h4[2] = f2bf(f.z); t.h4[3] = f2bf(f.w);
      *(uint2*)&su.p1.xs[row][xc] = t.u;
    }
    // stage weight chunks (already bf16, transposed)
#pragma unroll
    for (int m = 0; m < 3; ++m) {
      s16x8 w8 = *(const s16x8*)(wb + m * (NH * ND * NC) + wn * NC + c0 + wc);
      *(s16x8*)&su.p1.w[m][wn][wc] = w8;
    }
    __syncthreads();
    // compute: 2 row-tiles x 4 col-tiles x 3 matrices
    s16x8 a0 = *(const s16x8*)&su.p1.xs[r0 + l15][lg * 8];
    s16x8 a1 = *(const s16x8*)&su.p1.xs[r0 + 16 + l15][lg * 8];
#pragma unroll
    for (int nt = 0; nt < 4; ++nt) {
      s16x8 bq = *(const s16x8*)&su.p1.w[0][nt * 16 + l15][lg * 8];
      accq[0][nt] = MFMA16(a0, bq, accq[0][nt]);
      accq[1][nt] = MFMA16(a1, bq, accq[1][nt]);
      s16x8 bk = *(const s16x8*)&su.p1.w[1][nt * 16 + l15][lg * 8];
      acck[0][nt] = MFMA16(a0, bk, acck[0][nt]);
      acck[1][nt] = MFMA16(a1, bk, acck[1][nt]);
      s16x8 bv = *(const s16x8*)&su.p1.w[2][nt * 16 + l15][lg * 8];
      accv[0][nt] = MFMA16(a0, bv, accv[0][nt]);
      accv[1][nt] = MFMA16(a1, bv, accv[1][nt]);
    }
  }

  // write Q (scale 1/sqrt(D) folded in), K, V^T to LDS
#pragma unroll
  for (int mt = 0; mt < 2; ++mt)
#pragma unroll
    for (int nt = 0; nt < 4; ++nt) {
      int trow = r0 + 16 * mt + 4 * lg;
      int col = 16 * nt + l15;
#pragma unroll
      for (int r = 0; r < 4; ++r) {
        qs[trow + r][col] = f2bf(accq[mt][nt][r] * 0.125f);
        ks[trow + r][col] = f2bf(acck[mt][nt][r]);
      }
      union { unsigned short h4[4]; uint2 u; } t;
#pragma unroll
      for (int r = 0; r < 4; ++r) t.h4[r] = f2bf(accv[mt][nt][r]);
      *(uint2*)&vts[col][trow] = t.u;   // transpose: 4 consecutive s per lane
    }
  __syncthreads();

  // ---- phase 2: S = Q K^T (already scaled), mask, softmax ----
  f32x4 sacc[2][8];
#pragma unroll
  for (int i = 0; i < 2; ++i)
#pragma unroll
    for (int j = 0; j < 8; ++j) sacc[i][j] = f32x4{0.f, 0.f, 0.f, 0.f};

#pragma unroll
  for (int kd = 0; kd < 2; ++kd) {
    s16x8 aq0 = *(const s16x8*)&qs[r0 + l15][kd * 32 + lg * 8];
    s16x8 aq1 = *(const s16x8*)&qs[r0 + 16 + l15][kd * 32 + lg * 8];
#pragma unroll
    for (int nt = 0; nt < 8; ++nt) {
      s16x8 bk = *(const s16x8*)&ks[nt * 16 + l15][kd * 32 + lg * 8];
      sacc[0][nt] = MFMA16(aq0, bk, sacc[0][nt]);
      sacc[1][nt] = MFMA16(aq1, bk, sacc[1][nt]);
    }
  }

  float inv_[2][4];
#pragma unroll
  for (int mt = 0; mt < 2; ++mt)
#pragma unroll
    for (int r = 0; r < 4; ++r) {
      int trow = r0 + 16 * mt + 4 * lg + r;
      float mx = -1e30f;
#pragma unroll
      for (int nt = 0; nt < 8; ++nt) {
        bool valid = (nt * 16 + l15) <= trow;     // causal
        float v = valid ? sacc[mt][nt][r] : -1e30f;
        sacc[mt][nt][r] = v;
        mx = fmaxf(mx, v);
      }
#pragma unroll
      for (int off = 1; off < 16; off <<= 1) mx = fmaxf(mx, __shfl_xor(mx, off, 64));
      float sm = 0.f;
#pragma unroll
      for (int nt = 0; nt < 8; ++nt) {
        float e = __expf(sacc[mt][nt][r] - mx);   // masked -> exp(-huge) = 0
        sacc[mt][nt][r] = e;
        sm += e;
      }
#pragma unroll
      for (int off = 1; off < 16; off <<= 1) sm += __shfl_xor(sm, off, 64);
      inv_[mt][r] = 1.f / sm;
    }

  // ---- phase 3: O = P @ V, chunked over s (P staged into su.p3, 64 cols at a time) ----
  f32x4 oacc[2][4];
#pragma unroll
  for (int i = 0; i < 2; ++i)
#pragma unroll
    for (int j = 0; j < 4; ++j) oacc[i][j] = f32x4{0.f, 0.f, 0.f, 0.f};

#pragma unroll
  for (int c2 = 0; c2 < 2; ++c2) {
#pragma unroll
    for (int mt = 0; mt < 2; ++mt)
#pragma unroll
      for (int ntl = 0; ntl < 4; ++ntl) {
        int nt = c2 * 4 + ntl;
        int trow = r0 + 16 * mt + 4 * lg;
        int col = ntl * 16 + l15;
#pragma unroll
        for (int r = 0; r < 4; ++r)
          su.p3.p[trow + r][col] = f2bf(sacc[mt][nt][r] * inv_[mt][r]);
      }
    __syncthreads();
#pragma unroll
    for (int ks2 = 0; ks2 < 2; ++ks2) {
      s16x8 ap0 = *(const s16x8*)&su.p3.p[r0 + l15][ks2 * 32 + lg * 8];
      s16x8 ap1 = *(const s16x8*)&su.p3.p[r0 + 16 + l15][ks2 * 32 + lg * 8];
#pragma unroll
      for (int nt = 0; nt < 4; ++nt) {
        s16x8 bv = *(const s16x8*)&vts[nt * 16 + l15][c2 * 64 + ks2 * 32 + lg * 8];
        oacc[0][nt] = MFMA16(ap0, bv, oacc[0][nt]);
        oacc[1][nt] = MFMA16(ap1, bv, oacc[1][nt]);
      }
    }
    __syncthreads();
  }

  // epilogue: O[b][t][h*64+d] as bf16 (feeds projection GEMM)
  unsigned short* Ob = O + ((size_t)b * NTOK) * (NH * ND) + h * ND;
#pragma unroll
  for (int mt = 0; mt < 2; ++mt)
#pragma unroll
    for (int nt = 0; nt < 4; ++nt) {
      int trow = r0 + 16 * mt + 4 * lg;
      int col = nt * 16 + l15;
#pragma unroll
      for (int r = 0; r < 4; ++r)
        Ob[(size_t)(trow + r) * (NH * ND) + col] = f2bf(oacc[mt][nt][r]);
    }
}

// ---------------- kernel 2: out = O @ Wp + bp  (M=65536, N=384, K=384) ----------------
__global__ __launch_bounds__(256) void proj_gemm(
    const unsigned short* __restrict__ O, const unsigned short* __restrict__ wpT,
    const float* __restrict__ bp, float* __restrict__ out) {
  const int ntile = blockIdx.x >> 9;   // 0..2 (ntile-major so A-tile sharers hit same XCD)
  const int mtile = blockIdx.x & 511;
  const int m0 = mtile * 128, n0 = ntile * 128;
  const int tid = threadIdx.x;
  const int lane = tid & 63;
  const int l15 = lane & 15, lg = lane >> 4;
  const int r0 = (tid >> 6) * 32;

  __shared__ __align__(16) unsigned short as_[128][40];
  __shared__ __align__(16) unsigned short bs_[128][40];

  f32x4 acc[2][8];
#pragma unroll
  for (int i = 0; i < 2; ++i)
#pragma unroll
    for (int j = 0; j < 8; ++j) acc[i][j] = f32x4{0.f, 0.f, 0.f, 0.f};

  const int sr = tid >> 2, sc = (tid & 3) * 8;
  for (int kc = 0; kc < 12; ++kc) {
    int c0 = kc * 32;
    __syncthreads();
#pragma unroll
    for (int s = 0; s < 2; ++s) {
      int row = sr + 64 * s;
      *(s16x8*)&as_[row][sc] = *(const s16x8*)(O + (size_t)(m0 + row) * NC + c0 + sc);
      *(s16x8*)&bs_[row][sc] = *(const s16x8*)(wpT + (size_t)(n0 + row) * NC + c0 + sc);
    }
    __syncthreads();
    s16x8 a0 = *(const s16x8*)&as_[r0 + l15][lg * 8];
    s16x8 a1 = *(const s16x8*)&as_[r0 + 16 + l15][lg * 8];
#pragma unroll
    for (int nt = 0; nt < 8; ++nt) {
      s16x8 bb = *(const s16x8*)&bs_[nt * 16 + l15][lg * 8];
      acc[0][nt] = MFMA16(a0, bb, acc[0][nt]);
      acc[1][nt] = MFMA16(a1, bb, acc[1][nt]);
    }
  }
#pragma unroll
  for (int mt = 0; mt < 2; ++mt)
#pragma unroll
    for (int nt = 0; nt < 8; ++nt) {
      int trow = m0 + r0 + 16 * mt + 4 * lg;
      int col = n0 + nt * 16 + l15;
      float bias = bp[col];
#pragma unroll
      for (int r = 0; r < 4; ++r)
        out[(size_t)(trow + r) * NC + col] = acc[mt][nt][r] + bias;
    }
}

// ---------------- launch ----------------
extern "C" void kernel_launch(void* const* d_in, const int* in_sizes, int n_in,
                              void* d_out, int out_size, void* d_ws, size_t ws_size,
                              hipStream_t stream) {
  const float* x  = (const float*)d_in[0];
  const float* Wq = (const float*)d_in[1];
  const float* Wk = (const float*)d_in[2];
  const float* Wv = (const float*)d_in[3];
  const float* Wp = (const float*)d_in[4];
  const float* bp = (const float*)d_in[5];
  float* out = (float*)d_out;

  char* ws = (char*)d_ws;
  // ws layout: O bf16 [65536][384] @0 (50,331,648 B); wqkvT @50,331,648 (884,736 B);
  //            wpT @51,216,384 (294,912 B). Total ~49.2 MiB.
  unsigned short* O     = (unsigned short*)(ws);
  unsigned short* wqkvT = (unsigned short*)(ws + 50331648);
  unsigned short* wpT   = (unsigned short*)(ws + 51216384);

  convert_weights<<<2304, 256, 0, stream>>>(Wq, Wk, Wv, Wp, wqkvT, wpT);
  attn_fused<<<NB * NH, 256, 0, stream>>>(x, wqkvT, O);
  proj_gemm<<<3 * 512, 256, 0, stream>>>(O, wpT, bp, out);
}